// Round 15
// baseline (208.994 us; speedup 1.0000x reference)
//
#include <hip/hip_runtime.h>

#define T_TOK 16384
#define C_DIM 1024

typedef float f32x4 __attribute__((ext_vector_type(4)));
typedef float f32x16 __attribute__((ext_vector_type(16)));
typedef __bf16 bf16x8 __attribute__((ext_vector_type(8)));
typedef unsigned short u16x8 __attribute__((ext_vector_type(8)));
typedef unsigned short u16x4 __attribute__((ext_vector_type(4)));

__device__ __forceinline__ unsigned short f2bf(float f) {
  union { float f; unsigned u; } v; v.f = f;
  unsigned r = v.u + 0x7fffu + ((v.u >> 16) & 1u);
  return (unsigned short)(r >> 16);
}
__device__ __forceinline__ float bf2f(unsigned short h) {
  union { unsigned u; float f; } v; v.u = ((unsigned)h) << 16;
  return v.f;
}
__device__ __forceinline__ unsigned pk2(float a, float b) {
  return (unsigned)f2bf(a) | ((unsigned)f2bf(b) << 16);
}

// ---------------- f32 -> bf16 weight conversion (both weights, one launch) ----------------
__global__ __launch_bounds__(256) void cvt2_kernel(const float* __restrict__ wqkv,
                                                   const float* __restrict__ wout,
                                                   unsigned short* __restrict__ out) {
  int i = blockIdx.x * 256 + threadIdx.x;
  const float* src;
  size_t so;
  if (i < 786432) { src = wqkv; so = (size_t)i * 4; }
  else            { src = wout; so = (size_t)(i - 786432) * 4; }
  f32x4 v = *(const f32x4*)(src + so);
  u16x4 o;
#pragma unroll
  for (int j = 0; j < 4; ++j) o[j] = f2bf(v[j]);
  *(u16x4*)(out + (size_t)i * 4) = o;
}

// ---------------- RoPE table: [32 pos][32 dmod] float2 (cos,sin) ----------------
__global__ __launch_bounds__(256) void rope_tab_kernel(float* __restrict__ tab) {
  int idx = blockIdx.x * 256 + threadIdx.x;
  if (idx >= 1024) return;
  int mm = idx >> 5, d = idx & 31;
  float invf = powf(10000.f, -(float)d * (1.f / 32.f));
  float ang = (float)mm * invf;
  float s, c;
  sincosf(ang, &s, &c);
  tab[idx * 2] = c;
  tab[idx * 2 + 1] = s;
}

// ---------------- single-pass LayerNorm + transpose ----------------
__global__ __launch_bounds__(256) void ln_fused_kernel(const float* __restrict__ x,
                                                       const float* __restrict__ gamma,
                                                       const float* __restrict__ beta,
                                                       unsigned short* __restrict__ normed) {
  __shared__ float tile[1024][33];
  __shared__ float s1[8][32], s2[8][32];
  __shared__ float ms[32], rs[32];
  const int tid = threadIdx.x;
  const int t0 = blockIdx.x * 32;

  {
    const int tok = tid & 31, g = tid >> 5;
    float s = 0.f, ss = 0.f;
    const float* p = x + (size_t)(g * 128) * T_TOK + t0 + tok;
#pragma unroll 4
    for (int i = 0; i < 128; ++i) {
      float v = p[(size_t)i * T_TOK];
      tile[g * 128 + i][tok] = v;
      s += v; ss += v * v;
    }
    s1[g][tok] = s; s2[g][tok] = ss;
  }
  __syncthreads();
  if (tid < 32) {
    float S = 0.f, SS = 0.f;
#pragma unroll
    for (int g = 0; g < 8; ++g) { S += s1[g][tid]; SS += s2[g][tid]; }
    float m = S * (1.f / 1024.f);
    float var = SS * (1.f / 1024.f) - m * m;
    ms[tid] = m;
    rs[tid] = rsqrtf(var + 1e-5f);
  }
  __syncthreads();
  {
    const int tok = tid >> 3, cg = tid & 7;
    const float m = ms[tok], rr = rs[tok];
#pragma unroll
    for (int i = 0; i < 16; ++i) {
      int ch8 = cg * 8 + i * 64;
      u16x8 o;
#pragma unroll
      for (int j = 0; j < 8; ++j) {
        float v = tile[ch8 + j][tok];
        o[j] = f2bf((v - m) * rr * gamma[ch8 + j] + beta[ch8 + j]);
      }
      *(u16x8*)&normed[(size_t)(t0 + tok) * C_DIM + ch8] = o;
    }
  }
}

#define GLDS(gp, lp) \
  __builtin_amdgcn_global_load_lds((const __attribute__((address_space(1))) void*)(gp), \
                                   (__attribute__((address_space(3))) void*)(lp), 16, 0, 0)

#define BARF() do { __builtin_amdgcn_s_barrier(); asm volatile("" ::: "memory"); } while (0)
#define VMC(n) asm volatile("s_waitcnt vmcnt(" #n ")" ::: "memory")

// ======== fused QKV-projection + RoPE + windowed attention (2 blocks/CU) ========
// One block = (128-token tile tt) x (head h); grid 8 xcd * 16 tt * 16 h = 2048.
// 512 thr = 8 waves (2M x 4N); per-wave C: 64x48; BK=32, KT=32.
// LDS arena 51,200 B (staging 40,960 | epilogue 51,200) -> >=2 blocks/CU:
// co-resident block hides the per-tile VMC(0)+barrier drain (m114 overlap).
// Swizzle (32-col rows, 4 slots of 8): stage lane l pre-fetches global slot
// (l&3)^((l>>2)&3); read slot ((lane>>4)^(lane&3)) -> round-trips to kg.
__global__ __launch_bounds__(512, 2) void qkvattn_kernel(const unsigned short* __restrict__ A,
                                                         const unsigned short* __restrict__ Bq,
                                                         const float* __restrict__ ropeT,
                                                         unsigned short* __restrict__ aout) {
  __shared__ unsigned short arena[25600];  // 51,200 B
  unsigned short* LA = arena;              // staging: [2][128*32] (8,192 u16)
  unsigned short* LB = arena + 8192;       // staging: [2][192*32] (12,288 u16)
  unsigned short* QKl = arena;             // epilogue: [128][136] (17,408 u16)
  unsigned short* Vtl = arena + 17408;     // epilogue: [4][64][32] (8,192 u16)

  const int tid = threadIdx.x;
  const int w = tid >> 6, lane = tid & 63;
  const int wm = w >> 2, wn = w & 3;
  const int K = 1024, KT = 32;

  const int xcd = blockIdx.x & 7;
  const int ib = blockIdx.x >> 3;
  const int tt = xcd * 16 + (ib & 15);
  const int h = ib >> 4;
  const size_t m0 = (size_t)tt * 128;

  // staging source pre-swizzle: lane l covers row (l>>2), slot l&3 of a 16-row chunk
  const int preslot = ((lane & 3) ^ ((lane >> 2) & 3)) * 8;
  const int lrow = lane >> 2;

  // A chunk w: rows m0 + w*16 + lrow
  const unsigned short* gAc = A + (m0 + w * 16 + lrow) * (size_t)K + preslot;
  // B chunk c: panel row c*16+lrow; seg = c>>2 (q/k/v), row-in-seg = (c&3)*16+lrow
  const int c1 = w;          // all waves: chunk w
  const int c2 = 8 + w;      // waves 0-3: chunk 8+w
  const unsigned short* gBc1 = Bq + ((size_t)((c1 >> 2) * 1024 + h * 64 + (c1 & 3) * 16 + lrow)) * K + preslot;
  const unsigned short* gBc2 = Bq + ((size_t)((c2 >> 2) * 1024 + h * 64 + (c2 & 3) * 16 + lrow)) * K + preslot;

  auto stage = [&](int b, int kt) {
    const size_t k0 = (size_t)kt * 32;
    GLDS(gAc + k0, LA + b * 4096 + w * 512);
    GLDS(gBc1 + k0, LB + b * 6144 + c1 * 512);
    if (w < 4) GLDS(gBc2 + k0, LB + b * 6144 + c2 * 512);
  };

  f32x4 acc[4][3];
#pragma unroll
  for (int i = 0; i < 4; ++i)
#pragma unroll
    for (int j = 0; j < 3; ++j) acc[i][j] = (f32x4){0.f, 0.f, 0.f, 0.f};

  // read-side: row base (lane&15)*32 within a 16-row group; slot ((lane>>4)^(lane&3))*8
  const int off_r = (lane & 15) * 32;
  const int slot = (((lane >> 4) ^ (lane & 3)) * 8);

  bf16x8 aF[4], bF[3];

  // ---- prologue: stage t0; drain; barrier ----
  stage(0, 0);
  VMC(0);
  BARF();

  int bb = 0;
  for (int t = 0; t < KT; ++t, bb ^= 1) {
    const unsigned short* Ab = LA + bb * 4096 + (wm * 64) * 32;
    const unsigned short* Bb = LB + bb * 6144 + (wn * 48) * 32;

    // issue all reads (compiler inserts counted lgkm waits under the MFMAs)
#pragma unroll
    for (int mi = 0; mi < 4; ++mi)
      aF[mi] = *(const bf16x8*)&Ab[mi * 512 + off_r + slot];
#pragma unroll
    for (int ni = 0; ni < 3; ++ni)
      bF[ni] = *(const bf16x8*)&Bb[ni * 512 + off_r + slot];

    if (t + 1 < KT) stage(bb ^ 1, t + 1);

    __builtin_amdgcn_s_setprio(1);
#pragma unroll
    for (int mi = 0; mi < 4; ++mi)
#pragma unroll
      for (int ni = 0; ni < 3; ++ni)
        acc[mi][ni] = __builtin_amdgcn_mfma_f32_16x16x32_bf16(aF[mi], bF[ni], acc[mi][ni], 0, 0, 0);
    __builtin_amdgcn_s_setprio(0);

    VMC(0);   // next-tile stage landed; drain hidden by co-resident block
    BARF();
  }

  // ---- epilogue: repack C frags -> QKl [128][136] (q|k), Vtl [4][64][32] (v) ----
  __syncthreads();
#pragma unroll
  for (int mi = 0; mi < 4; ++mi)
#pragma unroll
    for (int ni = 0; ni < 3; ++ni) {
      const int j = wn * 48 + ni * 16 + (lane & 15);
#pragma unroll
      for (int r = 0; r < 4; ++r) {
        int tok = wm * 64 + mi * 16 + (lane >> 4) * 4 + r;
        unsigned short bv = f2bf(acc[mi][ni][r]);
        if (j < 128) {
          QKl[tok * 136 + j] = bv;
        } else {
          int d = j - 128;
          int mm = tok & 31, win = tok >> 5;
          Vtl[(win * 64 + d) * 32 + ((((mm >> 3) ^ (d ^ (d >> 2))) & 3) * 8 + (mm & 7))] = bv;
        }
      }
    }
  __syncthreads();

  // ---- per-wave window attention: waves 0-3 handle windows 0-3 ----
  if (w < 4) {
    const int m = lane & 31, hi = lane >> 5;
    const unsigned short* qp = QKl + (size_t)(w * 32 + m) * 136;
    u16x8 qv[4], kv[4];
#pragma unroll
    for (int s = 0; s < 4; ++s) {
      int off = s * 16 + hi * 8;
      qv[s] = *(const u16x8*)(qp + off);
      kv[s] = *(const u16x8*)(qp + 64 + off);
    }

    f32x4 ct[2][4];
    const float* tp = ropeT + (size_t)(m * 32 + hi * 8) * 2;
#pragma unroll
    for (int kp = 0; kp < 2; ++kp)
#pragma unroll
      for (int q = 0; q < 4; ++q)
        ct[kp][q] = *(const f32x4*)(tp + kp * 32 + q * 4);

    union FU { unsigned u[4]; bf16x8 v; };
    bf16x8 qfr[4], kfr[4];
#pragma unroll
    for (int ks = 0; ks < 4; ++ks) {
      const int kp = ks & 1;
      FU fq, fk;
#pragma unroll
      for (int jp = 0; jp < 4; ++jp) {
        float c0 = ct[kp][jp][0], s0 = ct[kp][jp][1];
        float c1f = ct[kp][jp][2], s1f = ct[kp][jp][3];
        float q0 = bf2f(qv[ks][2 * jp]), q1 = bf2f(qv[ks][2 * jp + 1]);
        float k0 = bf2f(kv[ks][2 * jp]), k1 = bf2f(kv[ks][2 * jp + 1]);
        float rq0, rq1, rk0, rk1;
        if (ks < 2) {
          rq0 = -bf2f(qv[ks + 2][2 * jp]); rq1 = -bf2f(qv[ks + 2][2 * jp + 1]);
          rk0 = -bf2f(kv[ks + 2][2 * jp]); rk1 = -bf2f(kv[ks + 2][2 * jp + 1]);
        } else {
          rq0 = bf2f(qv[ks - 2][2 * jp]); rq1 = bf2f(qv[ks - 2][2 * jp + 1]);
          rk0 = bf2f(kv[ks - 2][2 * jp]); rk1 = bf2f(kv[ks - 2][2 * jp + 1]);
        }
        fq.u[jp] = pk2(q0 * c0 + rq0 * s0, q1 * c1f + rq1 * s1f);
        fk.u[jp] = pk2(k0 * c0 + rk0 * s0, k1 * c1f + rk1 * s1f);
      }
      qfr[ks] = fq.v; kfr[ks] = fk.v;
    }

    f32x16 accS;
#pragma unroll
    for (int i = 0; i < 16; ++i) accS[i] = 0.f;
#pragma unroll
    for (int ks = 0; ks < 4; ++ks)
      accS = __builtin_amdgcn_mfma_f32_32x32x16_bf16(kfr[ks], qfr[ks], accS, 0, 0, 0);

    float p[16];
    float mx = -1e30f;
#pragma unroll
    for (int r = 0; r < 16; ++r) { p[r] = accS[r] * 0.125f; mx = fmaxf(mx, p[r]); }
    mx = fmaxf(mx, __shfl_xor(mx, 32, 64));
    float sum = 0.f;
#pragma unroll
    for (int r = 0; r < 16; ++r) { p[r] = __expf(p[r] - mx); sum += p[r]; }
    sum += __shfl_xor(sum, 32, 64);
    const float inv = 1.f / sum;
#pragma unroll
    for (int r = 0; r < 16; ++r) p[r] *= inv;

    bf16x8 pfr[2];
    {
      FU f0, f1;
      unsigned a0 = hi ? pk2(p[0], p[1]) : pk2(p[4], p[5]);
      unsigned a1 = hi ? pk2(p[2], p[3]) : pk2(p[6], p[7]);
      unsigned b0 = (unsigned)__shfl_xor((int)a0, 32, 64);
      unsigned b1 = (unsigned)__shfl_xor((int)a1, 32, 64);
      if (hi) { f0.u[0] = b0; f0.u[1] = b1; f0.u[2] = pk2(p[4], p[5]); f0.u[3] = pk2(p[6], p[7]); }
      else    { f0.u[0] = pk2(p[0], p[1]); f0.u[1] = pk2(p[2], p[3]); f0.u[2] = b0; f0.u[3] = b1; }
      unsigned a2 = hi ? pk2(p[8], p[9])   : pk2(p[12], p[13]);
      unsigned a3 = hi ? pk2(p[10], p[11]) : pk2(p[14], p[15]);
      unsigned b2 = (unsigned)__shfl_xor((int)a2, 32, 64);
      unsigned b3 = (unsigned)__shfl_xor((int)a3, 32, 64);
      if (hi) { f1.u[0] = b2; f1.u[1] = b3; f1.u[2] = pk2(p[12], p[13]); f1.u[3] = pk2(p[14], p[15]); }
      else    { f1.u[0] = pk2(p[8], p[9]); f1.u[1] = pk2(p[10], p[11]); f1.u[2] = b2; f1.u[3] = b3; }
      pfr[0] = f0.v; pfr[1] = f1.v;
    }

    f32x16 accO[2];
#pragma unroll
    for (int i = 0; i < 16; ++i) { accO[0][i] = 0.f; accO[1][i] = 0.f; }
    const int dl = lane & 31;
#pragma unroll
    for (int dh = 0; dh < 2; ++dh) {
      int d = dh * 32 + dl;
      int sx = (d ^ (d >> 2)) & 3;
#pragma unroll
      for (int ks = 0; ks < 2; ++ks) {
        bf16x8 vf = *(const bf16x8*)&Vtl[(w * 64 + d) * 32 + (((2 * ks + hi) ^ sx) & 3) * 8];
        accO[dh] = __builtin_amdgcn_mfma_f32_32x32x16_bf16(pfr[ks], vf, accO[dh], 0, 0, 0);
      }
    }

    const int W = tt * 4 + w;
#pragma unroll
    for (int r = 0; r < 16; ++r) {
      int n = (r & 3) + 8 * (r >> 2) + 4 * hi;
      size_t o = (size_t)(W * 32 + n) * 1024 + h * 64 + dl;
      aout[o] = f2bf(accO[0][r]);
      aout[o + 32] = f2bf(accO[1][r]);
    }
  }
}

// ================= 256x256 compiler-pipelined bf16 NT GEMM (GEMM2') =================
template <int EPI>
__global__ __launch_bounds__(512, 2) void gemm8p_kernel(const unsigned short* __restrict__ A,
                                                        const unsigned short* __restrict__ B,
                                                        unsigned short* __restrict__ Obf,
                                                        int ldo, int nbn, int K,
                                                        const float* __restrict__ Xadd,
                                                        float* __restrict__ Ofp) {
  __shared__ unsigned short Lds[2][2][2][8192];
  const int tid = threadIdx.x;
  const int w = tid >> 6, lane = tid & 63;
  const int wm = w >> 2, wn = w & 3;

  const int nbm = gridDim.x / nbn;
  const int xcd = blockIdx.x & 7;
  const int ib = blockIdx.x >> 3;
  int mt, nt;
  if ((nbm & 7) == 0) {
    const int mtpx = nbm >> 3;
    mt = xcd * mtpx + (ib % mtpx);
    nt = ib / mtpx;
  } else {
    const int ntpx = nbn >> 3;
    nt = xcd * ntpx + (ib % ntpx);
    mt = ib / ntpx;
  }
  const size_t m0 = (size_t)mt * 256, n0 = (size_t)nt * 256;

  const unsigned short* gA = A + (m0 + (lane >> 3)) * (size_t)K + ((lane & 7) ^ (lane >> 3)) * 8;
  const unsigned short* gB = B + (n0 + (lane >> 3)) * (size_t)K + ((lane & 7) ^ (lane >> 3)) * 8;
  const int wrow = w * 8;

  auto stageA = [&](int b, int h, int kt) {
    const unsigned short* g = gA + (size_t)(h * 128) * K + (size_t)kt * 64;
    GLDS(g + (size_t)wrow * K,        &Lds[0][b][h][wrow * 64]);
    GLDS(g + (size_t)(64 + wrow) * K, &Lds[0][b][h][(64 + wrow) * 64]);
  };
  auto stageB = [&](int b, int h, int kt) {
    const unsigned short* g = gB + (size_t)(h * 128) * K + (size_t)kt * 64;
    GLDS(g + (size_t)wrow * K,        &Lds[1][b][h][wrow * 64]);
    GLDS(g + (size_t)(64 + wrow) * K, &Lds[1][b][h][(64 + wrow) * 64]);
  };

  f32x4 acc[8][4];
#pragma unroll
  for (int i = 0; i < 8; ++i)
#pragma unroll
    for (int j = 0; j < 4; ++j) acc[i][j] = (f32x4){0.f, 0.f, 0.f, 0.f};

  const int KT = K >> 6;
  const int off_r = (lane & 15) * 64;
  const int slot0 = (((lane >> 4) ^ (lane & 7)) * 8);
  const int slot1 = slot0 ^ 32;
  const int boff = (wn & 1) * 4096;

  bf16x8 aLo[4][2], aHi[4][2], bLo[2][2], bHi[2][2];

  stageA(0, 0, 0); stageA(0, 1, 0); stageB(0, 0, 0); stageB(0, 1, 0);
  if (KT > 1) {
    stageB(1, 0, 1); stageB(1, 1, 1); stageA(1, 0, 1); stageA(1, 1, 1);
    VMC(8);
  } else {
    VMC(0);
  }
  BARF();

  int bb = 0;
  for (int t = 0; t < KT; ++t, bb ^= 1) {
    const unsigned short* Ab = &Lds[0][bb][wm][0];
    const unsigned short* Bb = &Lds[1][bb][wn >> 1][boff];

#pragma unroll
    for (int mi = 0; mi < 4; ++mi) {
      aLo[mi][0] = *(const bf16x8*)&Ab[mi * 1024 + off_r + slot0];
      aLo[mi][1] = *(const bf16x8*)&Ab[mi * 1024 + off_r + slot1];
    }
#pragma unroll
    for (int ni = 0; ni < 2; ++ni) {
      bLo[ni][0] = *(const bf16x8*)&Bb[ni * 1024 + off_r + slot0];
      bLo[ni][1] = *(const bf16x8*)&Bb[ni * 1024 + off_r + slot1];
      bHi[ni][0] = *(const bf16x8*)&Bb[(ni + 2) * 1024 + off_r + slot0];
      bHi[ni][1] = *(const bf16x8*)&Bb[(ni + 2) * 1024 + off_r + slot1];
    }

    __builtin_amdgcn_s_setprio(1);
#pragma unroll
    for (int mi = 0; mi < 4; ++mi)
#pragma unroll
      for (int ni = 0; ni < 2; ++ni)
#pragma unroll
        for (int ks = 0; ks < 2; ++ks)
          acc[mi][ni] = __builtin_amdgcn_mfma_f32_16x16x32_bf16(aLo[mi][ks], bLo[ni][ks], acc[mi][ni], 0, 0, 0);
    __builtin_amdgcn_s_setprio(0);

#pragma unroll
    for (int mi = 0; mi < 4; ++mi) {
      aHi[mi][0] = *(const bf16x8*)&Ab[(mi + 4) * 1024 + off_r + slot0];
      aHi[mi][1] = *(const bf16x8*)&Ab[(mi + 4) * 1024 + off_r + slot1];
    }

    __builtin_amdgcn_s_setprio(1);
#pragma unroll
    for (int mi = 0; mi < 4; ++mi)
#pragma unroll
      for (int ni = 0; ni < 2; ++ni)
#pragma unroll
        for (int ks = 0; ks < 2; ++ks)
          acc[mi][ni + 2] = __builtin_amdgcn_mfma_f32_16x16x32_bf16(aLo[mi][ks], bHi[ni][ks], acc[mi][ni + 2], 0, 0, 0);
    __builtin_amdgcn_s_setprio(0);
    BARF();

    if (t + 2 < KT) { stageB(bb, 0, t + 2); stageB(bb, 1, t + 2); }

    __builtin_amdgcn_s_setprio(1);
#pragma unroll
    for (int mi = 0; mi < 4; ++mi)
#pragma unroll
      for (int ni = 0; ni < 2; ++ni)
#pragma unroll
        for (int ks = 0; ks < 2; ++ks)
          acc[mi + 4][ni + 2] = __builtin_amdgcn_mfma_f32_16x16x32_bf16(aHi[mi][ks], bHi[ni][ks], acc[mi + 4][ni + 2], 0, 0, 0);
    __builtin_amdgcn_s_setprio(0);
    BARF();

    if (t + 2 < KT) { stageA(bb, 0, t + 2); stageA(bb, 1, t + 2); }

    __builtin_amdgcn_s_setprio(1);
#pragma unroll
    for (int mi = 0; mi < 4; ++mi)
#pragma unroll
      for (int ni = 0; ni < 2; ++ni)
#pragma unroll
        for (int ks = 0; ks < 2; ++ks)
          acc[mi + 4][ni] = __builtin_amdgcn_mfma_f32_16x16x32_bf16(aHi[mi][ks], bLo[ni][ks], acc[mi + 4][ni], 0, 0, 0);
    __builtin_amdgcn_s_setprio(0);

    if (t + 2 < KT) {
      VMC(8);
    } else {
      VMC(0);
    }
    BARF();
  }

  if (EPI == 0) {
    unsigned short* cw = &Lds[0][0][0][0] + (size_t)w * 8192;
#pragma unroll
    for (int mi = 0; mi < 8; ++mi)
#pragma unroll
      for (int ni = 0; ni < 4; ++ni)
#pragma unroll
        for (int r = 0; r < 4; ++r)
          cw[(mi * 16 + (lane >> 4) * 4 + r) * 64 + ni * 16 + (lane & 15)] = f2bf(acc[mi][ni][r]);
    const size_t gr0 = m0 + wm * 128;
    const size_t gc0 = n0 + wn * 64;
#pragma unroll
    for (int it = 0; it < 16; ++it) {
      int idx = it * 64 + lane;
      int rr = idx >> 3, c8 = (idx & 7) * 8;
      *(u16x8*)&Obf[(gr0 + rr) * (size_t)ldo + gc0 + c8] = *(const u16x8*)&cw[rr * 64 + c8];
    }
  } else {
    const size_t mrow0 = m0 + wm * 128 + (lane >> 4) * 4;
    const size_t ncol0 = n0 + wn * 64 + (lane & 15);
#pragma unroll
    for (int mi = 0; mi < 8; ++mi)
#pragma unroll
      for (int ni = 0; ni < 4; ++ni)
#pragma unroll
        for (int r = 0; r < 4; ++r) {
          size_t o = (mrow0 + mi * 16 + r) * T_TOK + ncol0 + ni * 16;
          Ofp[o] = acc[mi][ni][r] + Xadd[o];
        }
  }
}

extern "C" void kernel_launch(void* const* d_in, const int* in_sizes, int n_in,
                              void* d_out, int out_size, void* d_ws, size_t ws_size,
                              hipStream_t stream) {
  const float* x     = (const float*)d_in[0];
  const float* w_qkv = (const float*)d_in[1];
  const float* w_out = (const float*)d_in[2];
  const float* gamma = (const float*)d_in[3];
  const float* beta  = (const float*)d_in[4];

  char* ws = (char*)d_ws;
  unsigned short* wqkv_bf = (unsigned short*)(ws);                       // 6,291,456 B
  float* ropeT = (float*)(ws + 8519680);                                 // 8,192 B
  unsigned short* normed = (unsigned short*)(ws + 8527872);              // 33,554,432 B
  unsigned short* aout   = (unsigned short*)(ws + 42082304);             // 33,554,432 B
  unsigned short* wout_bf = wqkv_bf + 3145728;

  cvt2_kernel<<<4096, 256, 0, stream>>>(w_qkv, w_out, wqkv_bf);
  rope_tab_kernel<<<4, 256, 0, stream>>>(ropeT);
  // single-pass LayerNorm + transpose: grid 512 (32 tokens each)
  ln_fused_kernel<<<512, 256, 0, stream>>>(x, gamma, beta, normed);
  // fused QKV-proj + RoPE + attention: grid 8 xcd * 16 tt * 16 h = 2048
  qkvattn_kernel<<<2048, 512, 0, stream>>>(normed, wqkv_bf, ropeT, aout);
  // GEMM2': d_out (1024x16384) = w_out @ aout^T + x -> grid 4*64 = 256
  gemm8p_kernel<1><<<256, 512, 0, stream>>>(wout_bf, aout, nullptr, 0, 64, 1024,
                                            x, (float*)d_out);
}

// Round 16
// 198.239 us; speedup vs baseline: 1.0543x; 1.0543x over previous
//
#include <hip/hip_runtime.h>

#define T_TOK 16384
#define C_DIM 1024

typedef float f32x4 __attribute__((ext_vector_type(4)));
typedef float f32x16 __attribute__((ext_vector_type(16)));
typedef __bf16 bf16x8 __attribute__((ext_vector_type(8)));
typedef unsigned short u16x8 __attribute__((ext_vector_type(8)));
typedef unsigned short u16x4 __attribute__((ext_vector_type(4)));

__device__ __forceinline__ unsigned short f2bf(float f) {
  union { float f; unsigned u; } v; v.f = f;
  unsigned r = v.u + 0x7fffu + ((v.u >> 16) & 1u);
  return (unsigned short)(r >> 16);
}
__device__ __forceinline__ float bf2f(unsigned short h) {
  union { unsigned u; float f; } v; v.u = ((unsigned)h) << 16;
  return v.f;
}
__device__ __forceinline__ unsigned pk2(float a, float b) {
  return (unsigned)f2bf(a) | ((unsigned)f2bf(b) << 16);
}

// ---------------- f32 -> bf16 weight conversion (both weights, one launch) ----------------
__global__ __launch_bounds__(256) void cvt2_kernel(const float* __restrict__ wqkv,
                                                   const float* __restrict__ wout,
                                                   unsigned short* __restrict__ out) {
  // blocks 0..3071 cover w_qkv (3072*1024 f32); 3072..4095 cover w_out (1024*1024)
  int i = blockIdx.x * 256 + threadIdx.x;  // 4-float unit index
  const float* src;
  size_t so;
  if (i < 786432) { src = wqkv; so = (size_t)i * 4; }
  else            { src = wout; so = (size_t)(i - 786432) * 4; }
  f32x4 v = *(const f32x4*)(src + so);
  u16x4 o;
#pragma unroll
  for (int j = 0; j < 4; ++j) o[j] = f2bf(v[j]);
  *(u16x4*)(out + (size_t)i * 4) = o;
}

// ---------------- RoPE table: [32 pos][32 dmod] float2 (cos,sin) ----------------
__global__ __launch_bounds__(256) void rope_tab_kernel(float* __restrict__ tab) {
  int idx = blockIdx.x * 256 + threadIdx.x;
  if (idx >= 1024) return;
  int mm = idx >> 5, d = idx & 31;
  float invf = powf(10000.f, -(float)d * (1.f / 32.f));
  float ang = (float)mm * invf;
  float s, c;
  sincosf(ang, &s, &c);
  tab[idx * 2] = c;
  tab[idx * 2 + 1] = s;
}

// ---------------- single-pass LayerNorm + transpose ----------------
__global__ __launch_bounds__(256) void ln_fused_kernel(const float* __restrict__ x,
                                                       const float* __restrict__ gamma,
                                                       const float* __restrict__ beta,
                                                       unsigned short* __restrict__ normed) {
  __shared__ float tile[1024][33];
  __shared__ float s1[8][32], s2[8][32];
  __shared__ float ms[32], rs[32];
  const int tid = threadIdx.x;
  const int t0 = blockIdx.x * 32;

  {
    const int tok = tid & 31, g = tid >> 5;
    float s = 0.f, ss = 0.f;
    const float* p = x + (size_t)(g * 128) * T_TOK + t0 + tok;
#pragma unroll 4
    for (int i = 0; i < 128; ++i) {
      float v = p[(size_t)i * T_TOK];
      tile[g * 128 + i][tok] = v;
      s += v; ss += v * v;
    }
    s1[g][tok] = s; s2[g][tok] = ss;
  }
  __syncthreads();
  if (tid < 32) {
    float S = 0.f, SS = 0.f;
#pragma unroll
    for (int g = 0; g < 8; ++g) { S += s1[g][tid]; SS += s2[g][tid]; }
    float m = S * (1.f / 1024.f);
    float var = SS * (1.f / 1024.f) - m * m;
    ms[tid] = m;
    rs[tid] = rsqrtf(var + 1e-5f);
  }
  __syncthreads();
  {
    const int tok = tid >> 3, cg = tid & 7;
    const float m = ms[tok], rr = rs[tok];
#pragma unroll
    for (int i = 0; i < 16; ++i) {
      int ch8 = cg * 8 + i * 64;
      u16x8 o;
#pragma unroll
      for (int j = 0; j < 8; ++j) {
        float v = tile[ch8 + j][tok];
        o[j] = f2bf((v - m) * rr * gamma[ch8 + j] + beta[ch8 + j]);
      }
      *(u16x8*)&normed[(size_t)(t0 + tok) * C_DIM + ch8] = o;
    }
  }
}

#define GLDS(gp, lp) \
  __builtin_amdgcn_global_load_lds((const __attribute__((address_space(1))) void*)(gp), \
                                   (__attribute__((address_space(3))) void*)(lp), 16, 0, 0)

#define BARF() do { __builtin_amdgcn_s_barrier(); asm volatile("" ::: "memory"); } while (0)
#define VMC(n) asm volatile("s_waitcnt vmcnt(" #n ")" ::: "memory")

// ======== fused QKV-projection + RoPE + windowed attention ========
// One block = (256-token tile tt) x (head h). 512 thr = 8 waves (4M x 2N);
// per-wave C: 64x96. K-loop: R8 quadrant-interleaved schedule (reads aLo+bF ->
// q0 -> reads aHi -> q1 -> BARF -> stageB(t+2,cur) -> q2 -> BARF ->
// stageA(t+2,cur) -> q3 -> VMC(7) -> BARF).
__global__ __launch_bounds__(512, 2) void qkvattn_kernel(const unsigned short* __restrict__ A,
                                                         const unsigned short* __restrict__ Bq,
                                                         const float* __restrict__ ropeT,
                                                         unsigned short* __restrict__ aout) {
  __shared__ unsigned short arena[57344];  // 114,688 B
  unsigned short* LA = arena;              // [2][256*64]
  unsigned short* LB = arena + 32768;      // [2][192*64]
  unsigned short* QKl = arena;             // epilogue: [256][136]
  unsigned short* Vtl = arena + 34816;     // epilogue: [8][64][32]

  const int tid = threadIdx.x;
  const int w = tid >> 6, lane = tid & 63;
  const int wm = w >> 1, wn = w & 1;
  const int K = 1024, KT = 16;

  const int xcd = blockIdx.x & 7;
  const int ib = blockIdx.x >> 3;
  const int tt = xcd * 8 + (ib & 7);
  const int h = ib >> 3;
  const size_t m0 = (size_t)tt * 256;

  const int preslot = ((lane & 7) ^ (lane >> 3)) * 8;
  const unsigned short* gA = A + (m0 + w * 8 + (lane >> 3)) * (size_t)K + preslot;
  const unsigned short* gB0 = Bq + ((size_t)(0 + h * 64 + w * 8 + (lane >> 3))) * K + preslot;
  const unsigned short* gB1 = Bq + ((size_t)(1024 + h * 64 + w * 8 + (lane >> 3))) * K + preslot;
  const unsigned short* gB2 = Bq + ((size_t)(2048 + h * 64 + w * 8 + (lane >> 3))) * K + preslot;

  auto stageA4 = [&](int b, int kt) {
    const size_t k0 = (size_t)kt * 64;
    GLDS(gA + k0,                   LA + b * 16384 + (w * 8) * 64);
    GLDS(gA + (size_t)64 * K + k0,  LA + b * 16384 + (64 + w * 8) * 64);
    GLDS(gA + (size_t)128 * K + k0, LA + b * 16384 + (128 + w * 8) * 64);
    GLDS(gA + (size_t)192 * K + k0, LA + b * 16384 + (192 + w * 8) * 64);
  };
  auto stageB3 = [&](int b, int kt) {
    const size_t k0 = (size_t)kt * 64;
    GLDS(gB0 + k0, LB + b * 12288 + (w * 8) * 64);
    GLDS(gB1 + k0, LB + b * 12288 + (64 + w * 8) * 64);
    GLDS(gB2 + k0, LB + b * 12288 + (128 + w * 8) * 64);
  };

  f32x4 acc[4][6];
#pragma unroll
  for (int i = 0; i < 4; ++i)
#pragma unroll
    for (int j = 0; j < 6; ++j) acc[i][j] = (f32x4){0.f, 0.f, 0.f, 0.f};

  const int off_r = (lane & 15) * 64;
  const int slot0 = (((lane >> 4) ^ (lane & 7)) * 8);
  const int slot1 = slot0 ^ 32;

  bf16x8 aF[4][2], bF[6][2];

  // ---- prologue: stage t0 + t1; VMC(7) -> t0 landed ----
  stageA4(0, 0); stageB3(0, 0);
  stageA4(1, 1); stageB3(1, 1);
  VMC(7);
  BARF();

  int bb = 0;
  for (int t = 0; t < KT; ++t, bb ^= 1) {
    const unsigned short* Ab = LA + bb * 16384 + (wm * 64) * 64;
    const unsigned short* Bb = LB + bb * 12288 + (wn * 96) * 64;

#pragma unroll
    for (int mi = 0; mi < 2; ++mi) {
      aF[mi][0] = *(const bf16x8*)&Ab[mi * 1024 + off_r + slot0];
      aF[mi][1] = *(const bf16x8*)&Ab[mi * 1024 + off_r + slot1];
    }
#pragma unroll
    for (int ni = 0; ni < 6; ++ni) {
      bF[ni][0] = *(const bf16x8*)&Bb[ni * 1024 + off_r + slot0];
      bF[ni][1] = *(const bf16x8*)&Bb[ni * 1024 + off_r + slot1];
    }

    __builtin_amdgcn_s_setprio(1);
#pragma unroll
    for (int mi = 0; mi < 2; ++mi)
#pragma unroll
      for (int ni = 0; ni < 3; ++ni)
#pragma unroll
        for (int ks = 0; ks < 2; ++ks)
          acc[mi][ni] = __builtin_amdgcn_mfma_f32_16x16x32_bf16(aF[mi][ks], bF[ni][ks], acc[mi][ni], 0, 0, 0);
    __builtin_amdgcn_s_setprio(0);

#pragma unroll
    for (int mi = 2; mi < 4; ++mi) {
      aF[mi][0] = *(const bf16x8*)&Ab[mi * 1024 + off_r + slot0];
      aF[mi][1] = *(const bf16x8*)&Ab[mi * 1024 + off_r + slot1];
    }

    __builtin_amdgcn_s_setprio(1);
#pragma unroll
    for (int mi = 0; mi < 2; ++mi)
#pragma unroll
      for (int ni = 3; ni < 6; ++ni)
#pragma unroll
        for (int ks = 0; ks < 2; ++ks)
          acc[mi][ni] = __builtin_amdgcn_mfma_f32_16x16x32_bf16(aF[mi][ks], bF[ni][ks], acc[mi][ni], 0, 0, 0);
    __builtin_amdgcn_s_setprio(0);
    BARF();  // all waves' B ds_reads retired -> B region stageable

    if (t + 2 < KT) stageB3(bb, t + 2);

    __builtin_amdgcn_s_setprio(1);
#pragma unroll
    for (int mi = 2; mi < 4; ++mi)
#pragma unroll
      for (int ni = 3; ni < 6; ++ni)
#pragma unroll
        for (int ks = 0; ks < 2; ++ks)
          acc[mi][ni] = __builtin_amdgcn_mfma_f32_16x16x32_bf16(aF[mi][ks], bF[ni][ks], acc[mi][ni], 0, 0, 0);
    __builtin_amdgcn_s_setprio(0);
    BARF();  // all waves' A ds_reads retired -> A region stageable

    if (t + 2 < KT) stageA4(bb, t + 2);

    __builtin_amdgcn_s_setprio(1);
#pragma unroll
    for (int mi = 2; mi < 4; ++mi)
#pragma unroll
      for (int ni = 0; ni < 3; ++ni)
#pragma unroll
        for (int ks = 0; ks < 2; ++ks)
          acc[mi][ni] = __builtin_amdgcn_mfma_f32_16x16x32_bf16(aF[mi][ks], bF[ni][ks], acc[mi][ni], 0, 0, 0);
    __builtin_amdgcn_s_setprio(0);

    if (t + 2 < KT) {
      VMC(7);
    } else {
      VMC(0);
    }
    BARF();
  }

  // ---- epilogue: repack C frags -> QKl [256][136] (q|k), Vtl [8][64][32] (v) ----
  __syncthreads();
#pragma unroll
  for (int mi = 0; mi < 4; ++mi)
#pragma unroll
    for (int ni = 0; ni < 6; ++ni) {
      const int j = wn * 96 + ni * 16 + (lane & 15);
#pragma unroll
      for (int r = 0; r < 4; ++r) {
        int tok = wm * 64 + mi * 16 + (lane >> 4) * 4 + r;
        unsigned short bv = f2bf(acc[mi][ni][r]);
        if (wn == 0 || ni < 2) {
          QKl[tok * 136 + j] = bv;
        } else {
          int d = j - 128;
          int mm = tok & 31, win = tok >> 5;
          Vtl[(win * 64 + d) * 32 + ((((mm >> 3) ^ (d ^ (d >> 2))) & 3) * 8 + (mm & 7))] = bv;
        }
      }
    }
  __syncthreads();

  // ---- per-wave window attention (wave w = window w of this tile) ----
  {
    const int m = lane & 31, hi = lane >> 5;
    const unsigned short* qp = QKl + (size_t)(w * 32 + m) * 136;
    u16x8 qv[4], kv[4];
#pragma unroll
    for (int s = 0; s < 4; ++s) {
      int off = s * 16 + hi * 8;
      qv[s] = *(const u16x8*)(qp + off);
      kv[s] = *(const u16x8*)(qp + 64 + off);
    }

    f32x4 ct[2][4];
    const float* tp = ropeT + (size_t)(m * 32 + hi * 8) * 2;
#pragma unroll
    for (int kp = 0; kp < 2; ++kp)
#pragma unroll
      for (int q = 0; q < 4; ++q)
        ct[kp][q] = *(const f32x4*)(tp + kp * 32 + q * 4);

    union FU { unsigned u[4]; bf16x8 v; };
    bf16x8 qfr[4], kfr[4];
#pragma unroll
    for (int ks = 0; ks < 4; ++ks) {
      const int kp = ks & 1;
      FU fq, fk;
#pragma unroll
      for (int jp = 0; jp < 4; ++jp) {
        float c0 = ct[kp][jp][0], s0 = ct[kp][jp][1];
        float c1 = ct[kp][jp][2], s1 = ct[kp][jp][3];
        float q0 = bf2f(qv[ks][2 * jp]), q1 = bf2f(qv[ks][2 * jp + 1]);
        float k0 = bf2f(kv[ks][2 * jp]), k1 = bf2f(kv[ks][2 * jp + 1]);
        float rq0, rq1, rk0, rk1;
        if (ks < 2) {
          rq0 = -bf2f(qv[ks + 2][2 * jp]); rq1 = -bf2f(qv[ks + 2][2 * jp + 1]);
          rk0 = -bf2f(kv[ks + 2][2 * jp]); rk1 = -bf2f(kv[ks + 2][2 * jp + 1]);
        } else {
          rq0 = bf2f(qv[ks - 2][2 * jp]); rq1 = bf2f(qv[ks - 2][2 * jp + 1]);
          rk0 = bf2f(kv[ks - 2][2 * jp]); rk1 = bf2f(kv[ks - 2][2 * jp + 1]);
        }
        fq.u[jp] = pk2(q0 * c0 + rq0 * s0, q1 * c1 + rq1 * s1);
        fk.u[jp] = pk2(k0 * c0 + rk0 * s0, k1 * c1 + rk1 * s1);
      }
      qfr[ks] = fq.v; kfr[ks] = fk.v;
    }

    f32x16 accS;
#pragma unroll
    for (int i = 0; i < 16; ++i) accS[i] = 0.f;
#pragma unroll
    for (int ks = 0; ks < 4; ++ks)
      accS = __builtin_amdgcn_mfma_f32_32x32x16_bf16(kfr[ks], qfr[ks], accS, 0, 0, 0);

    float p[16];
    float mx = -1e30f;
#pragma unroll
    for (int r = 0; r < 16; ++r) { p[r] = accS[r] * 0.125f; mx = fmaxf(mx, p[r]); }
    mx = fmaxf(mx, __shfl_xor(mx, 32, 64));
    float sum = 0.f;
#pragma unroll
    for (int r = 0; r < 16; ++r) { p[r] = __expf(p[r] - mx); sum += p[r]; }
    sum += __shfl_xor(sum, 32, 64);
    const float inv = 1.f / sum;
#pragma unroll
    for (int r = 0; r < 16; ++r) p[r] *= inv;

    bf16x8 pfr[2];
    {
      FU f0, f1;
      unsigned a0 = hi ? pk2(p[0], p[1]) : pk2(p[4], p[5]);
      unsigned a1 = hi ? pk2(p[2], p[3]) : pk2(p[6], p[7]);
      unsigned b0 = (unsigned)__shfl_xor((int)a0, 32, 64);
      unsigned b1 = (unsigned)__shfl_xor((int)a1, 32, 64);
      if (hi) { f0.u[0] = b0; f0.u[1] = b1; f0.u[2] = pk2(p[4], p[5]); f0.u[3] = pk2(p[6], p[7]); }
      else    { f0.u[0] = pk2(p[0], p[1]); f0.u[1] = pk2(p[2], p[3]); f0.u[2] = b0; f0.u[3] = b1; }
      unsigned a2 = hi ? pk2(p[8], p[9])   : pk2(p[12], p[13]);
      unsigned a3 = hi ? pk2(p[10], p[11]) : pk2(p[14], p[15]);
      unsigned b2 = (unsigned)__shfl_xor((int)a2, 32, 64);
      unsigned b3 = (unsigned)__shfl_xor((int)a3, 32, 64);
      if (hi) { f1.u[0] = b2; f1.u[1] = b3; f1.u[2] = pk2(p[12], p[13]); f1.u[3] = pk2(p[14], p[15]); }
      else    { f1.u[0] = pk2(p[8], p[9]); f1.u[1] = pk2(p[10], p[11]); f1.u[2] = b2; f1.u[3] = b3; }
      pfr[0] = f0.v; pfr[1] = f1.v;
    }

    f32x16 accO[2];
#pragma unroll
    for (int i = 0; i < 16; ++i) { accO[0][i] = 0.f; accO[1][i] = 0.f; }
    const int dl = lane & 31;
#pragma unroll
    for (int dh = 0; dh < 2; ++dh) {
      int d = dh * 32 + dl;
      int sx = (d ^ (d >> 2)) & 3;
#pragma unroll
      for (int ks = 0; ks < 2; ++ks) {
        bf16x8 vf = *(const bf16x8*)&Vtl[(w * 64 + d) * 32 + (((2 * ks + hi) ^ sx) & 3) * 8];
        accO[dh] = __builtin_amdgcn_mfma_f32_32x32x16_bf16(pfr[ks], vf, accO[dh], 0, 0, 0);
      }
    }

    const int W = tt * 8 + w;
#pragma unroll
    for (int r = 0; r < 16; ++r) {
      int n = (r & 3) + 8 * (r >> 2) + 4 * hi;
      size_t o = (size_t)(W * 32 + n) * 1024 + h * 64 + dl;
      aout[o] = f2bf(accO[0][r]);
      aout[o + 32] = f2bf(accO[1][r]);
    }
  }
}

// ================= 256x256 compiler-pipelined bf16 NT GEMM (GEMM2') =================
template <int EPI>
__global__ __launch_bounds__(512, 2) void gemm8p_kernel(const unsigned short* __restrict__ A,
                                                        const unsigned short* __restrict__ B,
                                                        unsigned short* __restrict__ Obf,
                                                        int ldo, int nbn, int K,
                                                        const float* __restrict__ Xadd,
                                                        float* __restrict__ Ofp) {
  __shared__ unsigned short Lds[2][2][2][8192];
  const int tid = threadIdx.x;
  const int w = tid >> 6, lane = tid & 63;
  const int wm = w >> 2, wn = w & 3;

  const int nbm = gridDim.x / nbn;
  const int xcd = blockIdx.x & 7;
  const int ib = blockIdx.x >> 3;
  int mt, nt;
  if ((nbm & 7) == 0) {
    const int mtpx = nbm >> 3;
    mt = xcd * mtpx + (ib % mtpx);
    nt = ib / mtpx;
  } else {
    const int ntpx = nbn >> 3;
    nt = xcd * ntpx + (ib % ntpx);
    mt = ib / ntpx;
  }
  const size_t m0 = (size_t)mt * 256, n0 = (size_t)nt * 256;

  const unsigned short* gA = A + (m0 + (lane >> 3)) * (size_t)K + ((lane & 7) ^ (lane >> 3)) * 8;
  const unsigned short* gB = B + (n0 + (lane >> 3)) * (size_t)K + ((lane & 7) ^ (lane >> 3)) * 8;
  const int wrow = w * 8;

  auto stageA = [&](int b, int h, int kt) {
    const unsigned short* g = gA + (size_t)(h * 128) * K + (size_t)kt * 64;
    GLDS(g + (size_t)wrow * K,        &Lds[0][b][h][wrow * 64]);
    GLDS(g + (size_t)(64 + wrow) * K, &Lds[0][b][h][(64 + wrow) * 64]);
  };
  auto stageB = [&](int b, int h, int kt) {
    const unsigned short* g = gB + (size_t)(h * 128) * K + (size_t)kt * 64;
    GLDS(g + (size_t)wrow * K,        &Lds[1][b][h][wrow * 64]);
    GLDS(g + (size_t)(64 + wrow) * K, &Lds[1][b][h][(64 + wrow) * 64]);
  };

  f32x4 acc[8][4];
#pragma unroll
  for (int i = 0; i < 8; ++i)
#pragma unroll
    for (int j = 0; j < 4; ++j) acc[i][j] = (f32x4){0.f, 0.f, 0.f, 0.f};

  const int KT = K >> 6;
  const int off_r = (lane & 15) * 64;
  const int slot0 = (((lane >> 4) ^ (lane & 7)) * 8);
  const int slot1 = slot0 ^ 32;
  const int boff = (wn & 1) * 4096;

  bf16x8 aLo[4][2], aHi[4][2], bLo[2][2], bHi[2][2];

  stageA(0, 0, 0); stageA(0, 1, 0); stageB(0, 0, 0); stageB(0, 1, 0);
  if (KT > 1) {
    stageB(1, 0, 1); stageB(1, 1, 1); stageA(1, 0, 1); stageA(1, 1, 1);
    VMC(8);
  } else {
    VMC(0);
  }
  BARF();

  int bb = 0;
  for (int t = 0; t < KT; ++t, bb ^= 1) {
    const unsigned short* Ab = &Lds[0][bb][wm][0];
    const unsigned short* Bb = &Lds[1][bb][wn >> 1][boff];

#pragma unroll
    for (int mi = 0; mi < 4; ++mi) {
      aLo[mi][0] = *(const bf16x8*)&Ab[mi * 1024 + off_r + slot0];
      aLo[mi][1] = *(const bf16x8*)&Ab[mi * 1024 + off_r + slot1];
    }
#pragma unroll
    for (int ni = 0; ni < 2; ++ni) {
      bLo[ni][0] = *(const bf16x8*)&Bb[ni * 1024 + off_r + slot0];
      bLo[ni][1] = *(const bf16x8*)&Bb[ni * 1024 + off_r + slot1];
      bHi[ni][0] = *(const bf16x8*)&Bb[(ni + 2) * 1024 + off_r + slot0];
      bHi[ni][1] = *(const bf16x8*)&Bb[(ni + 2) * 1024 + off_r + slot1];
    }

    __builtin_amdgcn_s_setprio(1);
#pragma unroll
    for (int mi = 0; mi < 4; ++mi)
#pragma unroll
      for (int ni = 0; ni < 2; ++ni)
#pragma unroll
        for (int ks = 0; ks < 2; ++ks)
          acc[mi][ni] = __builtin_amdgcn_mfma_f32_16x16x32_bf16(aLo[mi][ks], bLo[ni][ks], acc[mi][ni], 0, 0, 0);
    __builtin_amdgcn_s_setprio(0);

#pragma unroll
    for (int mi = 0; mi < 4; ++mi) {
      aHi[mi][0] = *(const bf16x8*)&Ab[(mi + 4) * 1024 + off_r + slot0];
      aHi[mi][1] = *(const bf16x8*)&Ab[(mi + 4) * 1024 + off_r + slot1];
    }

    __builtin_amdgcn_s_setprio(1);
#pragma unroll
    for (int mi = 0; mi < 4; ++mi)
#pragma unroll
      for (int ni = 0; ni < 2; ++ni)
#pragma unroll
        for (int ks = 0; ks < 2; ++ks)
          acc[mi][ni + 2] = __builtin_amdgcn_mfma_f32_16x16x32_bf16(aLo[mi][ks], bHi[ni][ks], acc[mi][ni + 2], 0, 0, 0);
    __builtin_amdgcn_s_setprio(0);
    BARF();

    if (t + 2 < KT) { stageB(bb, 0, t + 2); stageB(bb, 1, t + 2); }

    __builtin_amdgcn_s_setprio(1);
#pragma unroll
    for (int mi = 0; mi < 4; ++mi)
#pragma unroll
      for (int ni = 0; ni < 2; ++ni)
#pragma unroll
        for (int ks = 0; ks < 2; ++ks)
          acc[mi + 4][ni + 2] = __builtin_amdgcn_mfma_f32_16x16x32_bf16(aHi[mi][ks], bHi[ni][ks], acc[mi + 4][ni + 2], 0, 0, 0);
    __builtin_amdgcn_s_setprio(0);
    BARF();

    if (t + 2 < KT) { stageA(bb, 0, t + 2); stageA(bb, 1, t + 2); }

    __builtin_amdgcn_s_setprio(1);
#pragma unroll
    for (int mi = 0; mi < 4; ++mi)
#pragma unroll
      for (int ni = 0; ni < 2; ++ni)
#pragma unroll
        for (int ks = 0; ks < 2; ++ks)
          acc[mi + 4][ni] = __builtin_amdgcn_mfma_f32_16x16x32_bf16(aHi[mi][ks], bLo[ni][ks], acc[mi + 4][ni], 0, 0, 0);
    __builtin_amdgcn_s_setprio(0);

    if (t + 2 < KT) {
      VMC(8);
    } else {
      VMC(0);
    }
    BARF();
  }

  if (EPI == 0) {
    unsigned short* cw = &Lds[0][0][0][0] + (size_t)w * 8192;
#pragma unroll
    for (int mi = 0; mi < 8; ++mi)
#pragma unroll
      for (int ni = 0; ni < 4; ++ni)
#pragma unroll
        for (int r = 0; r < 4; ++r)
          cw[(mi * 16 + (lane >> 4) * 4 + r) * 64 + ni * 16 + (lane & 15)] = f2bf(acc[mi][ni][r]);
    const size_t gr0 = m0 + wm * 128;
    const size_t gc0 = n0 + wn * 64;
#pragma unroll
    for (int it = 0; it < 16; ++it) {
      int idx = it * 64 + lane;
      int rr = idx >> 3, c8 = (idx & 7) * 8;
      *(u16x8*)&Obf[(gr0 + rr) * (size_t)ldo + gc0 + c8] = *(const u16x8*)&cw[rr * 64 + c8];
    }
  } else {
    const size_t mrow0 = m0 + wm * 128 + (lane >> 4) * 4;
    const size_t ncol0 = n0 + wn * 64 + (lane & 15);
#pragma unroll
    for (int mi = 0; mi < 8; ++mi)
#pragma unroll
      for (int ni = 0; ni < 4; ++ni)
#pragma unroll
        for (int r = 0; r < 4; ++r) {
          size_t o = (mrow0 + mi * 16 + r) * T_TOK + ncol0 + ni * 16;
          Ofp[o] = acc[mi][ni][r] + Xadd[o];
        }
  }
}

extern "C" void kernel_launch(void* const* d_in, const int* in_sizes, int n_in,
                              void* d_out, int out_size, void* d_ws, size_t ws_size,
                              hipStream_t stream) {
  const float* x     = (const float*)d_in[0];
  const float* w_qkv = (const float*)d_in[1];
  const float* w_out = (const float*)d_in[2];
  const float* gamma = (const float*)d_in[3];
  const float* beta  = (const float*)d_in[4];

  char* ws = (char*)d_ws;
  unsigned short* wqkv_bf = (unsigned short*)(ws);                       // 6,291,456 B
  // wout_bf lives contiguously after wqkv_bf: single cvt2 launch covers both
  float* ropeT = (float*)(ws + 8519680);                                 // 8,192 B
  unsigned short* normed = (unsigned short*)(ws + 8527872);              // 33,554,432 B
  unsigned short* aout   = (unsigned short*)(ws + 42082304);             // 33,554,432 B
  unsigned short* wout_bf = wqkv_bf + 3145728;

  cvt2_kernel<<<4096, 256, 0, stream>>>(w_qkv, w_out, wqkv_bf);
  rope_tab_kernel<<<4, 256, 0, stream>>>(ropeT);
  // single-pass LayerNorm + transpose: grid 512 (32 tokens each)
  ln_fused_kernel<<<512, 256, 0, stream>>>(x, gamma, beta, normed);
  // fused QKV-proj + RoPE + attention: grid 8 xcd * 8 tt * 16 h = 1024
  qkvattn_kernel<<<1024, 512, 0, stream>>>(normed, wqkv_bf, ropeT, aout);
  // GEMM2': d_out (1024x16384) = w_out @ aout^T + x -> grid 4*64 = 256
  gemm8p_kernel<1><<<256, 512, 0, stream>>>(wout_bf, aout, nullptr, 0, 64, 1024,
                                            x, (float*)d_out);
}